// Round 7
// baseline (263.923 us; speedup 1.0000x reference)
//
#include <hip/hip_runtime.h>
#include <math.h>

// ConvSlimCapsule3D, round 11 (= round 10 split + swapped-MFMA vote stores).
// r10 evidence: conv_votes 148us, WRITE_SIZE 213MB vs 134 logical (1.6x write amp),
// 64x b16 scatter stores/thread (~67M store instrs). Fix: swap mfma operands ->
// D[row=channel][col=voxel]; each fragment's 4 floats = 4 contiguous channels ->
// one 8B half4 store; 16 stores/thread, no write amplification. votes layout and
// routing kernel unchanged.

typedef _Float16 half8 __attribute__((ext_vector_type(8)));
typedef _Float16 half4 __attribute__((ext_vector_type(4)));
typedef float f32x4 __attribute__((ext_vector_type(4)));
typedef float f32x2 __attribute__((ext_vector_type(2)));

__device__ __forceinline__ void gload_lds16(const void* g, void* l) {
    __builtin_amdgcn_global_load_lds(
        (const __attribute__((address_space(1))) void*)g,
        (__attribute__((address_space(3))) void*)l, 16, 0, 0);
}

// lane^1 exchange on the VALU (DPP quad_perm(1,0,3,2)).
__device__ __forceinline__ float swap1(float x) {
    return __builtin_bit_cast(float, __builtin_amdgcn_update_dpp(
        0, __builtin_bit_cast(int, x), 0xB1, 0xF, 0xF, true));
}
__device__ __forceinline__ f32x2 swap2(f32x2 v) {
    f32x2 r; r[0] = swap1(v[0]); r[1] = swap1(v[1]); return r;
}
// add with DPP-permuted value (ctrl must be a compile-time constant)
template <int CTRL>
__device__ __forceinline__ float dpp_add(float x) {
    const int p = __builtin_amdgcn_update_dpp(
        0, __builtin_bit_cast(int, x), CTRL, 0xF, 0xF, true);
    return x + __builtin_bit_cast(float, p);
}
// sum across each aligned 8-lane group (VALU only)
__device__ __forceinline__ float sum8(float x) {
    x = dpp_add<0xB1>(x);    // quad_perm(1,0,3,2): ^1
    x = dpp_add<0x4E>(x);    // quad_perm(2,3,0,1): ^2
    x = dpp_add<0x141>(x);   // row_half_mirror: cross-quad within 8
    return x;
}

// ---- merged prep: blocks [0,2312) = xt transpose; [2312,2536) = weights ----
__global__ __launch_bounds__(256) void prep_all(const float* __restrict__ x,
                                                const float* __restrict__ cw,
                                                _Float16* __restrict__ xt,
                                                _Float16* __restrict__ wh2) {
    const int t = threadIdx.x;
    if (blockIdx.x >= 2312) {
        const int idx = (blockIdx.x - 2312) * 256 + t;   // 57344
        const int n   = idx / 448;
        const int rem = idx - n * 448;
        const int c   = rem >> 5;
        const int k   = rem & 31;
        const int tp  = k >> 4, ca = k & 15;
        const int tap = 2 * c + tp;
        float v = (tap < 27) ? cw[n * 432 + ca * 27 + tap] : 0.0f;
        wh2[c * 4096 + n * 32 + k] = (_Float16)v;
        return;
    }
    __shared__ half8 ldsv[544];           // [wp 0..33][ch 0..127] f16 = 8704 B
    _Float16* lds = (_Float16*)ldsv;
    const int bz = blockIdx.x;            // 2*34*34 = 2312
    const int yp = bz % 34;
    const int t2 = bz / 34;
    const int zp = t2 % 34;
    const int b  = t2 / 34;
    _Float16* dst = xt + (size_t)(((b * 34 + zp) * 34 + yp)) * 34 * 128;
    const bool interior = (zp >= 1 && zp <= 32 && yp >= 1 && yp <= 32);
    if (!interior) {
        const half8 z8 = (half8)(_Float16)0.f;
        for (int idx = t; idx < 544; idx += 256)
            *(half8*)(dst + idx * 8) = z8;
        return;
    }
    const int c  = t >> 1;                // 0..127
    const int wh = (t & 1) << 4;          // 0 or 16
    const float* sp = x + (size_t)(b * 128 + c) * 32768
                        + (zp - 1) * 1024 + (yp - 1) * 32 + wh;
    #pragma unroll
    for (int e4 = 0; e4 < 4; e4++) {
        const f32x4 v = *(const f32x4*)(sp + e4 * 4);
        #pragma unroll
        for (int e = 0; e < 4; e++)
            lds[(wh + e4 * 4 + e + 1) * 128 + c] = (_Float16)v[e];
    }
    if (t < 128) lds[t] = (_Float16)0.f;                // wp = 0
    else         lds[33 * 128 + (t - 128)] = (_Float16)0.f; // wp = 33
    __syncthreads();
    for (int idx = t; idx < 544; idx += 256)
        *(half8*)(dst + idx * 8) = *(const half8*)(lds + idx * 8);
}

// =================== split kernel 1: conv -> votes (global f16) ==================
// votes layout: [vox 65536][i 8][ch 128] f16, vox = gid*32 + v (logical order).
__global__ __launch_bounds__(512, 4) void conv_votes_kernel(
    const _Float16* __restrict__ xt,  // (2,34,34,34,128) f16 padded
    const _Float16* __restrict__ wh2, // (14,128,32) f16 reordered
    const float* __restrict__ cb,     // (128,)
    _Float16* __restrict__ votes)     // (65536, 8, 128) f16
{
    __shared__ half8 slabv[4928];     // 78,848B: slab only
    char* smem = (char*)slabv;

    const int t  = threadIdx.x;
    const int bx = blockIdx.x;
    const int gid = ((bx & 7) << 8) | (bx >> 3);   // XCD-contiguous (2048 = 8*256)
    const int h = gid & 31;
    const int d = (gid >> 5) & 31;
    const int b = gid >> 10;

    const int wid = t >> 6, lane = t & 63;

    // stage slab: 308 rows x 256B via global_load_lds (row rr = zy*34 + j; slot s
    // holds ch-unit u = s ^ (j&15); phantom rows 306/307 read a valid source).
    {
        const int lrow = lane >> 4;
        const int s    = lane & 15;
        const int bzd  = b * 34 + d;
        for (int i = wid; i < 77; i += 8) {
            const int rr0 = i << 2;
            const int rr  = rr0 + lrow;
            int zy = rr / 34;
            int j  = rr - zy * 34;
            if (rr >= 306) { zy = 0; j = 0; }
            const int dz  = (zy * 11) >> 5;
            const int dy  = zy - dz * 3;
            const int uu  = s ^ (j & 15);
            const unsigned off =
                ((((unsigned)(bzd + dz) * 34u + (unsigned)(h + dy)) * 34u
                  + (unsigned)j) << 8) + (unsigned)(uu << 4);
            gload_lds16((const char*)xt + off, smem + (rr0 << 8));
        }
    }
    __syncthreads();   // B0: slab staged

    // GEMM (swapped operands): A = weights (M=128 ch), B = slab (N=32 vox), K=448.
    // Per-lane fragment contents identical to r10; only C/D interpretation flips:
    // D row = ch n = nt*16 + q*4 + reg, D col = vox = vt*16 + r.
    const int q = lane >> 4, r = lane & 15;
    const int qlow = q & 1, tphase = q >> 1;

    int zyA[14], dxA[14];
    #pragma unroll
    for (int c = 0; c < 14; c++) {
        int tap = 2 * c + tphase;
        if (tap > 26) tap = 0;             // tap27: weight k-slots are zero
        const int dz = tap / 9, r9 = tap - dz * 9;
        const int dy = r9 / 3,  dxx = r9 - dy * 3;
        zyA[c] = dz * 3 + dy;
        dxA[c] = dxx;
    }
    const int uA = wid * 2 + qlow;

    const _Float16* bp0 = wh2 + r * 32 + q * 8;
    const _Float16* bp1 = bp0 + 2048;

    f32x4 acc[2][8];                       // [vt voxel-half][nt channel-tile]
    #pragma unroll
    for (int i = 0; i < 2; i++)
        #pragma unroll
        for (int j = 0; j < 8; j++) acc[i][j] = (f32x4)0.f;

    #pragma unroll
    for (int c = 0; c < 14; c++) {
        half8 bf[8];
        #pragma unroll
        for (int nt = 0; nt < 4; nt++) {
            bf[nt]     = *(const half8*)(bp0 + c * 4096 + nt * 512);
            bf[nt + 4] = *(const half8*)(bp1 + c * 4096 + nt * 512);
        }
        const int jw = r + dxA[c];
        const int js = jw & 15;
        const char* abase = smem + zyA[c] * 8704 + jw * 256 + ((uA ^ js) << 4);
        const half8 af0 = *(const half8*)abase;            // voxel half 0
        const half8 af1 = *(const half8*)(abase + 4096);   // voxel half 1
        #pragma unroll
        for (int nt = 0; nt < 8; nt++) {
            acc[0][nt] = __builtin_amdgcn_mfma_f32_16x16x32_f16(bf[nt], af0,
                                                                acc[0][nt], 0, 0, 0);
            acc[1][nt] = __builtin_amdgcn_mfma_f32_16x16x32_f16(bf[nt], af1,
                                                                acc[1][nt], 0, 0, 0);
        }
    }

    // vote store: fragment's 4 floats = 4 contiguous channels -> one 8B store.
    // 16 stores/thread (was 64 b16 scatters). No LDS, no barrier.
    f32x4 cbq[8];
    #pragma unroll
    for (int nt = 0; nt < 8; nt++)
        cbq[nt] = *(const f32x4*)&cb[nt * 16 + q * 4];
    #pragma unroll
    for (int vt = 0; vt < 2; vt++) {
        _Float16* vp = votes + (size_t)(gid * 32 + vt * 16 + r) * 1024
                             + wid * 128 + q * 4;
        #pragma unroll
        for (int nt = 0; nt < 8; nt++) {
            half4 hv;
            #pragma unroll
            for (int e = 0; e < 4; e++)
                hv[e] = (_Float16)(acc[vt][nt][e] + cbq[nt][e]);
            *(half4*)(vp + nt * 16) = hv;
        }
    }
}

// =================== split kernel 2: routing (all-register, no LDS) ==============
// thread = (vox, o): lane = vox8*8 + o -> loads are 1KB/instr coalesced.
__global__ __launch_bounds__(256) void routing_kernel(
    const _Float16* __restrict__ votes, // (65536, 8, 128) f16
    const float* __restrict__ bias,     // (8,16)
    float* __restrict__ out)            // (2,8,16,32,32,32) f32
{
    const int t   = threadIdx.x;
    const int o   = t & 7;
    const int vq  = t >> 3;                       // 0..31
    const int vox = blockIdx.x * 32 + vq;         // 0..65535
    const _Float16* vp = votes + (size_t)vox * 1024 + o * 16;

    f32x2 vf2[8][8];                              // [i][atom pair]
    #pragma unroll
    for (int i = 0; i < 8; i++) {
        #pragma unroll
        for (int ah = 0; ah < 2; ah++) {
            const half8 hv = *(const half8*)(vp + i * 128 + ah * 8);
            #pragma unroll
            for (int k = 0; k < 4; k++) {
                f32x2 e; e[0] = (float)hv[2 * k]; e[1] = (float)hv[2 * k + 1];
                vf2[i][ah * 4 + k] = e;
            }
        }
    }

    float vn[8];
    #pragma unroll
    for (int i = 0; i < 8; i++) {
        f32x2 s = (f32x2)0.f;
        #pragma unroll
        for (int k = 0; k < 8; k++)
            s = __builtin_elementwise_fma(vf2[i][k], vf2[i][k], s);
        vn[i] = sqrtf(s[0] + s[1]);
    }
    f32x2 bl2[8];
    #pragma unroll
    for (int k = 0; k < 8; k++)
        bl2[k] = *(const f32x2*)&bias[o * 16 + 2 * k];

    float rt[8], lgr[8];
    #pragma unroll
    for (int i = 0; i < 8; i++) { rt[i] = 0.125f; lgr[i] = 0.f; }
    f32x2 pre2[8];

    for (int it = 0; it < 3; it++) {
        #pragma unroll
        for (int k = 0; k < 8; k++) pre2[k] = bl2[k];
        #pragma unroll
        for (int i = 0; i < 8; i++) {
            f32x2 rtv; rtv[0] = rt[i]; rtv[1] = rt[i];
            #pragma unroll
            for (int k = 0; k < 8; k++)
                pre2[k] = __builtin_elementwise_fma(rtv, vf2[i][k], pre2[k]);
        }
        if (it == 2) break;

        f32x2 s2v = (f32x2)0.f;
        #pragma unroll
        for (int k = 0; k < 8; k++)
            s2v = __builtin_elementwise_fma(pre2[k], pre2[k], s2v);
        const float pn = sqrtf(s2v[0] + s2v[1]);

        float ex[8];
        #pragma unroll
        for (int i = 0; i < 8; i++) {
            f32x2 dv = (f32x2)0.f;
            #pragma unroll
            for (int k = 0; k < 8; k++)
                dv = __builtin_elementwise_fma(pre2[k], vf2[i][k], dv);
            lgr[i] += __fdividef(dv[0] + dv[1], fmaxf(pn * vn[i], 1e-8f));
            ex[i] = __expf(lgr[i]);    // |lgr| <= 2, no max-sub needed
        }
        #pragma unroll
        for (int i = 0; i < 8; i++) {
            const float s = sum8(ex[i]);            // softmax over o (8 lanes)
            rt[i] = __fdividef(ex[i], s);
        }
    }

    // squash + store
    f32x2 s2v = (f32x2)0.f;
    #pragma unroll
    for (int k = 0; k < 8; k++)
        s2v = __builtin_elementwise_fma(pre2[k], pre2[k], s2v);
    const float n2 = s2v[0] + s2v[1];
    const float nn = sqrtf(n2);
    const float scale = __fdividef(n2, (1.f + n2) * (nn + 1e-12f));
    const int b = vox >> 15;
    const size_t sp = (size_t)(vox & 32767);
    float* op = out + ((size_t)(b * 8 + o) * 16) * 32768 + sp;
    #pragma unroll
    for (int k = 0; k < 8; k++) {
        op[(size_t)(2 * k) * 32768]     = pre2[k][0] * scale;
        op[(size_t)(2 * k + 1) * 32768] = pre2[k][1] * scale;
    }
}

// =================== fallback: proven r8 fused kernel ===========================
__global__ __launch_bounds__(512, 4) void caps_mfma_kernel(
    const _Float16* __restrict__ xt, const _Float16* __restrict__ wh2,
    const float* __restrict__ cb, const float* __restrict__ bias,
    float* __restrict__ out)
{
    __shared__ half8 slabv[4928];
    char* smem = (char*)slabv;
    _Float16* Vh = (_Float16*)slabv;
    float* RT = (float*)slabv;
    float* LG = (float*)slabv + 2304;

    const int t  = threadIdx.x;
    const int bx = blockIdx.x;
    const int gid = ((bx & 7) << 8) | (bx >> 3);
    const int h = gid & 31;
    const int d = (gid >> 5) & 31;
    const int b = gid >> 10;
    const int wid = t >> 6, lane = t & 63;
    {
        const int lrow = lane >> 4;
        const int s    = lane & 15;
        const int bzd  = b * 34 + d;
        for (int i = wid; i < 77; i += 8) {
            const int rr0 = i << 2;
            const int rr  = rr0 + lrow;
            int zy = rr / 34;
            int j  = rr - zy * 34;
            if (rr >= 306) { zy = 0; j = 0; }
            const int dz  = (zy * 11) >> 5;
            const int dy  = zy - dz * 3;
            const int uu  = s ^ (j & 15);
            const unsigned off =
                ((((unsigned)(bzd + dz) * 34u + (unsigned)(h + dy)) * 34u
                  + (unsigned)j) << 8) + (unsigned)(uu << 4);
            gload_lds16((const char*)xt + off, smem + (rr0 << 8));
        }
    }
    __syncthreads();

    const int q = lane >> 4, r = lane & 15;
    const int qlow = q & 1, tphase = q >> 1;
    int zyA[14], dxA[14];
    #pragma unroll
    for (int c = 0; c < 14; c++) {
        int tap = 2 * c + tphase;
        if (tap > 26) tap = 0;
        const int dz = tap / 9, r9 = tap - dz * 9;
        const int dy = r9 / 3,  dxx = r9 - dy * 3;
        zyA[c] = dz * 3 + dy;
        dxA[c] = dxx;
    }
    const int uA = wid * 2 + qlow;
    const _Float16* bp0 = wh2 + r * 32 + q * 8;
    const _Float16* bp1 = bp0 + 2048;
    f32x4 acc[2][8];
    #pragma unroll
    for (int i = 0; i < 2; i++)
        #pragma unroll
        for (int j = 0; j < 8; j++) acc[i][j] = (f32x4)0.f;
    #pragma unroll
    for (int c = 0; c < 14; c++) {
        half8 bf[8];
        #pragma unroll
        for (int nt = 0; nt < 4; nt++) {
            bf[nt]     = *(const half8*)(bp0 + c * 4096 + nt * 512);
            bf[nt + 4] = *(const half8*)(bp1 + c * 4096 + nt * 512);
        }
        const int jw = r + dxA[c];
        const int js = jw & 15;
        const char* abase = smem + zyA[c] * 8704 + jw * 256 + ((uA ^ js) << 4);
        const half8 af0 = *(const half8*)abase;
        const half8 af1 = *(const half8*)(abase + 4096);
        #pragma unroll
        for (int nt = 0; nt < 8; nt++) {
            acc[0][nt] = __builtin_amdgcn_mfma_f32_16x16x32_f16(af0, bf[nt],
                                                                acc[0][nt], 0, 0, 0);
            acc[1][nt] = __builtin_amdgcn_mfma_f32_16x16x32_f16(af1, bf[nt],
                                                                acc[1][nt], 0, 0, 0);
        }
    }
    __syncthreads();
    float cbv[8];
    #pragma unroll
    for (int nt = 0; nt < 8; nt++) cbv[nt] = cb[nt * 16 + r];
    #pragma unroll
    for (int mt = 0; mt < 2; mt++) {
        #pragma unroll
        for (int nt = 0; nt < 8; nt++) {
            const int n = nt * 16 + r;
            #pragma unroll
            for (int reg = 0; reg < 4; reg++) {
                const int v = mt * 16 + q * 4 + reg;
                Vh[v * 1032 + wid * 128 + n] = (_Float16)(acc[mt][nt][reg] + cbv[nt]);
            }
        }
    }
    __syncthreads();
    const int p = t >> 1, half = t & 1;
    const int vv = p & 31, oo = p >> 5;
    const int ib = half << 2;
    f32x2 vf2[4][8];
    #pragma unroll
    for (int ii = 0; ii < 4; ii++) {
        #pragma unroll
        for (int ah = 0; ah < 2; ah++) {
            const half8 hv =
                *(const half8*)&Vh[vv * 1032 + (ib + ii) * 128 + oo * 16 + ah * 8];
            #pragma unroll
            for (int k = 0; k < 4; k++) {
                f32x2 e; e[0] = (float)hv[2 * k]; e[1] = (float)hv[2 * k + 1];
                vf2[ii][ah * 4 + k] = e;
            }
        }
    }
    __syncthreads();
    float vn[4];
    #pragma unroll
    for (int ii = 0; ii < 4; ii++) {
        f32x2 s = (f32x2)0.f;
        #pragma unroll
        for (int k = 0; k < 8; k++)
            s = __builtin_elementwise_fma(vf2[ii][k], vf2[ii][k], s);
        vn[ii] = sqrtf(s[0] + s[1]);
    }
    f32x2 bl2[8];
    #pragma unroll
    for (int k = 0; k < 8; k++)
        bl2[k] = *(const f32x2*)&bias[oo * 16 + 2 * k];
    float rt[4], lgr[4];
    #pragma unroll
    for (int ii = 0; ii < 4; ii++) { rt[ii] = 0.125f; lgr[ii] = 0.f; }
    f32x2 pre2[8];
    for (int it = 0; it < 3; it++) {
        #pragma unroll
        for (int k = 0; k < 8; k++) pre2[k] = (f32x2)0.f;
        #pragma unroll
        for (int ii = 0; ii < 4; ii++) {
            f32x2 rtv; rtv[0] = rt[ii]; rtv[1] = rt[ii];
            #pragma unroll
            for (int k = 0; k < 8; k++)
                pre2[k] = __builtin_elementwise_fma(rtv, vf2[ii][k], pre2[k]);
        }
        #pragma unroll
        for (int k = 0; k < 8; k++)
            pre2[k] = bl2[k] + pre2[k] + swap2(pre2[k]);
        if (it == 2) break;
        f32x2 s2v = (f32x2)0.f;
        #pragma unroll
        for (int k = 0; k < 8; k++)
            s2v = __builtin_elementwise_fma(pre2[k], pre2[k], s2v);
        const float pn = sqrtf(s2v[0] + s2v[1]);
        #pragma unroll
        for (int ii = 0; ii < 4; ii++) {
            f32x2 dv = (f32x2)0.f;
            #pragma unroll
            for (int k = 0; k < 8; k++)
                dv = __builtin_elementwise_fma(pre2[k], vf2[ii][k], dv);
            lgr[ii] += __fdividef(dv[0] + dv[1], fmaxf(pn * vn[ii], 1e-8f));
            LG[vv * 72 + (ib + ii) * 8 + oo] = lgr[ii];
        }
        __syncthreads();
        {
            const f32x4 E = *(const f32x4*)&LG[vv * 72 + oo * 8 + half * 4];
            f32x4 exv; float ps = 0.f;
            #pragma unroll
            for (int k = 0; k < 4; k++) { exv[k] = __expf(E[k]); ps += exv[k]; }
            const float sum = ps + swap1(ps);
            const float rs = __fdividef(1.f, sum);
            f32x4 w4;
            #pragma unroll
            for (int k = 0; k < 4; k++) w4[k] = exv[k] * rs;
            *(f32x4*)&RT[vv * 72 + oo * 8 + half * 4] = w4;
        }
        __syncthreads();
        #pragma unroll
        for (int ii = 0; ii < 4; ii++)
            rt[ii] = RT[vv * 72 + (ib + ii) * 8 + oo];
    }
    f32x2 s2v = (f32x2)0.f;
    #pragma unroll
    for (int k = 0; k < 8; k++)
        s2v = __builtin_elementwise_fma(pre2[k], pre2[k], s2v);
    const float n2 = s2v[0] + s2v[1];
    const float nn = sqrtf(n2);
    const float scale = __fdividef(n2, (1.f + n2) * (nn + 1e-12f));
    const size_t sp = (size_t)d * 1024 + h * 32 + vv;
    #pragma unroll
    for (int a = 0; a < 8; a++) {
        const float vlo = pre2[(a >> 1)][a & 1];
        const float vhi = pre2[4 + (a >> 1)][a & 1];
        const float pv  = half ? vhi : vlo;
        out[((size_t)((b * 8 + oo) * 16 + half * 8 + a)) * 32768 + sp] = pv * scale;
    }
}

extern "C" void kernel_launch(void* const* d_in, const int* in_sizes, int n_in,
                              void* d_out, int out_size, void* d_ws, size_t ws_size,
                              hipStream_t stream) {
    const float* x    = (const float*)d_in[0];
    const float* cw   = (const float*)d_in[1];
    const float* cb   = (const float*)d_in[2];
    const float* bias = (const float*)d_in[3];
    float* out = (float*)d_out;
    _Float16* wh2 = (_Float16*)d_ws;                     // 114,688 B
    _Float16* xt  = (_Float16*)((char*)d_ws + 114688);   // 20,123,648 B
    const size_t WS_SPLIT = 114688ull + 20123648ull + 134217728ull;  // 154.5 MB

    hipLaunchKernelGGL(prep_all, dim3(2536), dim3(256), 0, stream, x, cw, xt, wh2);
    if (ws_size >= WS_SPLIT) {
        _Float16* votes = (_Float16*)((char*)d_ws + 114688 + 20123648);
        hipLaunchKernelGGL(conv_votes_kernel, dim3(2048), dim3(512), 0, stream,
                           xt, wh2, cb, votes);
        hipLaunchKernelGGL(routing_kernel, dim3(2048), dim3(256), 0, stream,
                           votes, bias, out);
    } else {
        hipLaunchKernelGGL(caps_mfma_kernel, dim3(2048), dim3(512), 0, stream,
                           xt, wh2, cb, bias, out);
    }
}

// Round 8
// 212.499 us; speedup vs baseline: 1.2420x; 1.2420x over previous
//
#include <hip/hip_runtime.h>
#include <math.h>

// ConvSlimCapsule3D, round 12: revert to fused r8 caps kernel (141.7us proven;
// the r9-r11 split's 268MB vote round-trip costs more than the convoy it fixed)
// + rewritten prep: one 744-block kernel.
//  - interior transpose blocks (256): block=(b,z,y-quarter); wave reads one
//    channel's 8yx32w f32 panel = 1KB contiguous (was 32-way 32B scatter);
//    LDS [272][136-pad] f16; write-out 8.7KB contiguous runs.
//  - halo-zero blocks (264) + weight blocks (224) folded in; 3 launches -> 2.

typedef _Float16 half8 __attribute__((ext_vector_type(8)));
typedef float f32x4 __attribute__((ext_vector_type(4)));
typedef float f32x2 __attribute__((ext_vector_type(2)));

__device__ __forceinline__ void gload_lds16(const void* g, void* l) {
    __builtin_amdgcn_global_load_lds(
        (const __attribute__((address_space(1))) void*)g,
        (__attribute__((address_space(3))) void*)l, 16, 0, 0);
}

// lane^1 exchange on the VALU (DPP quad_perm(1,0,3,2)).
__device__ __forceinline__ float swap1(float x) {
    return __builtin_bit_cast(float, __builtin_amdgcn_update_dpp(
        0, __builtin_bit_cast(int, x), 0xB1, 0xF, 0xF, true));
}
__device__ __forceinline__ f32x2 swap2(f32x2 v) {
    f32x2 r; r[0] = swap1(v[0]); r[1] = swap1(v[1]); return r;
}

// ---- prep_all: 744 blocks x 256 threads ----
// [0,256):   interior xt transpose. block = (b, z, yq): b=bid>>7, z=(bid>>2)&31,
//            y0=(bid&3)*8. Reads x[b][ch][z][y0..y0+7][*] (1KB/wave contiguous),
//            writes xt[b][z+1][y0+1..y0+8][wp 0..33][ch] with wp halo zeroed.
// [256,520): zero halo rows: zp in {0,33} x all yp, and zp 1..32 x yp in {0,33}.
// [520,744): weights: cw f32 (n=128,ca=16,tap=27) -> wh2 f16 [c=14][n=128][k=32],
//            k=tp*16+ca, tap=2c+tp, tap 27 zeroed.
__global__ __launch_bounds__(256) void prep_all(const float* __restrict__ x,
                                                const float* __restrict__ cw,
                                                _Float16* __restrict__ xt,
                                                _Float16* __restrict__ wh2) {
    __shared__ _Float16 lds[272 * 136];   // 73,984 B (interior blocks only)
    const int t   = threadIdx.x;
    const int bid = blockIdx.x;

    if (bid < 256) {
        const int b  = bid >> 7;
        const int z  = (bid >> 2) & 31;
        const int y0 = (bid & 3) << 3;
        // zero wp=0 / wp=33 rows (16 rows x 16 units; one half8 per thread)
        {
            const int rw = t >> 4, u = t & 15;
            const int y = rw >> 1, wp = (rw & 1) * 33;
            *(half8*)&lds[(y * 34 + wp) * 136 + u * 8] = (half8)(_Float16)0.f;
        }
        const float* xb = x + (size_t)b * 4194304 + z * 1024 + y0 * 32;
        #pragma unroll 4
        for (int i = 0; i < 32; i++) {
            const int idx4 = i * 256 + t;          // 0..8191
            const int ch = idx4 >> 6;              // 0..127 (1 ch per wave)
            const int y  = (idx4 >> 3) & 7;
            const int w4 = idx4 & 7;
            const f32x4 v = *(const f32x4*)(xb + (size_t)ch * 32768 + y * 32 + w4 * 4);
            const int rbase = y * 34 + w4 * 4 + 1; // wp = w+1
            #pragma unroll
            for (int e = 0; e < 4; e++)
                lds[(rbase + e) * 136 + ch] = (_Float16)v[e];
        }
        __syncthreads();
        _Float16* dst = xt + ((size_t)((b * 34 + z + 1) * 34 + y0 + 1)) * 34 * 128;
        #pragma unroll
        for (int k = 0; k < 17; k++) {
            const int idx = k * 256 + t;           // 0..4351
            const int vox = idx >> 4, u = idx & 15;
            *(half8*)(dst + (size_t)vox * 128 + u * 8) =
                *(const half8*)&lds[vox * 136 + u * 8];
        }
        return;
    }
    if (bid < 520) {
        const int rid = bid - 256;                 // 0..263
        const int b = rid / 132, rr = rid - b * 132;
        int zp, yp;
        if (rr < 68) { zp = (rr >= 34) ? 33 : 0; yp = rr % 34; }
        else { const int r2 = rr - 68; zp = 1 + (r2 >> 1); yp = (r2 & 1) ? 33 : 0; }
        _Float16* dst = xt + ((size_t)((b * 34 + zp) * 34 + yp)) * 34 * 128;
        const half8 z8 = (half8)(_Float16)0.f;
        for (int idx = t; idx < 544; idx += 256)
            *(half8*)(dst + idx * 8) = z8;
        return;
    }
    {
        const int idx = (bid - 520) * 256 + t;     // 0..57343
        const int n   = idx / 448;
        const int rem = idx - n * 448;
        const int c   = rem >> 5;
        const int k   = rem & 31;
        const int tp  = k >> 4, ca = k & 15;
        const int tap = 2 * c + tp;
        float v = (tap < 27) ? cw[n * 432 + ca * 27 + tap] : 0.0f;
        wh2[c * 4096 + n * 32 + k] = (_Float16)v;
    }
}

// =================== fused caps kernel (r8, 141.7us proven) =====================
__global__ __launch_bounds__(512, 4) void caps_mfma_kernel(
    const _Float16* __restrict__ xt,  // (2,34,34,34,128) f16 padded
    const _Float16* __restrict__ wh2, // (14,128,32) f16 reordered
    const float* __restrict__ cb,     // (128,)
    const float* __restrict__ bias,   // (8,16)
    float* __restrict__ out)          // (2,8,16,32,32,32) f32
{
    // 78,848 B: slab = 306 live rows (zy 0..8 x j 0..33) + 2 phantom, x 256B.
    // Votes (66,048B) overlay slab after B1; RT(2304 f32)+LG(2304 f32) after B3.
    __shared__ half8 slabv[4928];
    char* smem = (char*)slabv;
    _Float16* Vh = (_Float16*)slabv;
    float* RT = (float*)slabv;
    float* LG = (float*)slabv + 2304;

    const int t  = threadIdx.x;
    const int bx = blockIdx.x;
    const int gid = ((bx & 7) << 8) | (bx >> 3);   // XCD-contiguous (2048 = 8*256)
    const int h = gid & 31;
    const int d = (gid >> 5) & 31;
    const int b = gid >> 10;

    const int wid = t >> 6, lane = t & 63;

    // stage slab: 308 rows x 256B via global_load_lds
    {
        const int lrow = lane >> 4;
        const int s    = lane & 15;
        const int bzd  = b * 34 + d;
        for (int i = wid; i < 77; i += 8) {
            const int rr0 = i << 2;
            const int rr  = rr0 + lrow;
            int zy = rr / 34;
            int j  = rr - zy * 34;
            if (rr >= 306) { zy = 0; j = 0; }
            const int dz  = (zy * 11) >> 5;
            const int dy  = zy - dz * 3;
            const int uu  = s ^ (j & 15);
            const unsigned off =
                ((((unsigned)(bzd + dz) * 34u + (unsigned)(h + dy)) * 34u
                  + (unsigned)j) << 8) + (unsigned)(uu << 4);
            gload_lds16((const char*)xt + off, smem + (rr0 << 8));
        }
    }
    __syncthreads();   // B0: slab staged

    // GEMM: M=256, N=128, K=448; wave tile M32xN128
    const int q = lane >> 4, r = lane & 15;
    const int qlow = q & 1, tphase = q >> 1;

    int zyA[14], dxA[14];
    #pragma unroll
    for (int c = 0; c < 14; c++) {
        int tap = 2 * c + tphase;
        if (tap > 26) tap = 0;
        const int dz = tap / 9, r9 = tap - dz * 9;
        const int dy = r9 / 3,  dxx = r9 - dy * 3;
        zyA[c] = dz * 3 + dy;
        dxA[c] = dxx;
    }
    const int uA = wid * 2 + qlow;
    const _Float16* bp0 = wh2 + r * 32 + q * 8;
    const _Float16* bp1 = bp0 + 2048;

    f32x4 acc[2][8];
    #pragma unroll
    for (int i = 0; i < 2; i++)
        #pragma unroll
        for (int j = 0; j < 8; j++) acc[i][j] = (f32x4)0.f;

    #pragma unroll
    for (int c = 0; c < 14; c++) {
        half8 bf[8];
        #pragma unroll
        for (int nt = 0; nt < 4; nt++) {
            bf[nt]     = *(const half8*)(bp0 + c * 4096 + nt * 512);
            bf[nt + 4] = *(const half8*)(bp1 + c * 4096 + nt * 512);
        }
        const int jw = r + dxA[c];
        const int js = jw & 15;
        const char* abase = smem + zyA[c] * 8704 + jw * 256 + ((uA ^ js) << 4);
        const half8 af0 = *(const half8*)abase;
        const half8 af1 = *(const half8*)(abase + 4096);
        #pragma unroll
        for (int nt = 0; nt < 8; nt++) {
            acc[0][nt] = __builtin_amdgcn_mfma_f32_16x16x32_f16(af0, bf[nt],
                                                                acc[0][nt], 0, 0, 0);
            acc[1][nt] = __builtin_amdgcn_mfma_f32_16x16x32_f16(af1, bf[nt],
                                                                acc[1][nt], 0, 0, 0);
        }
    }

    __syncthreads();   // B1: slab reads done -> votes overlay

    float cbv[8];
    #pragma unroll
    for (int nt = 0; nt < 8; nt++) cbv[nt] = cb[nt * 16 + r];
    #pragma unroll
    for (int mt = 0; mt < 2; mt++) {
        #pragma unroll
        for (int nt = 0; nt < 8; nt++) {
            const int n = nt * 16 + r;
            #pragma unroll
            for (int reg = 0; reg < 4; reg++) {
                const int v = mt * 16 + q * 4 + reg;
                Vh[v * 1032 + wid * 128 + n] = (_Float16)(acc[mt][nt][reg] + cbv[nt]);
            }
        }
    }
    __syncthreads();   // B2: vote writes visible

    // routing: 512 threads = 256 (v,o) pairs x 2 in_dim-halves
    const int p = t >> 1, half = t & 1;
    const int vv = p & 31, oo = p >> 5;
    const int ib = half << 2;
    f32x2 vf2[4][8];
    #pragma unroll
    for (int ii = 0; ii < 4; ii++) {
        #pragma unroll
        for (int ah = 0; ah < 2; ah++) {
            const half8 hv =
                *(const half8*)&Vh[vv * 1032 + (ib + ii) * 128 + oo * 16 + ah * 8];
            #pragma unroll
            for (int k = 0; k < 4; k++) {
                f32x2 e; e[0] = (float)hv[2 * k]; e[1] = (float)hv[2 * k + 1];
                vf2[ii][ah * 4 + k] = e;
            }
        }
    }
    __syncthreads();   // B3: vote reads done -> RT/LG overlay

    float vn[4];
    #pragma unroll
    for (int ii = 0; ii < 4; ii++) {
        f32x2 s = (f32x2)0.f;
        #pragma unroll
        for (int k = 0; k < 8; k++)
            s = __builtin_elementwise_fma(vf2[ii][k], vf2[ii][k], s);
        vn[ii] = sqrtf(s[0] + s[1]);
    }
    f32x2 bl2[8];
    #pragma unroll
    for (int k = 0; k < 8; k++)
        bl2[k] = *(const f32x2*)&bias[oo * 16 + 2 * k];
    float rt[4], lgr[4];
    #pragma unroll
    for (int ii = 0; ii < 4; ii++) { rt[ii] = 0.125f; lgr[ii] = 0.f; }
    f32x2 pre2[8];
    for (int it = 0; it < 3; it++) {
        #pragma unroll
        for (int k = 0; k < 8; k++) pre2[k] = (f32x2)0.f;
        #pragma unroll
        for (int ii = 0; ii < 4; ii++) {
            f32x2 rtv; rtv[0] = rt[ii]; rtv[1] = rt[ii];
            #pragma unroll
            for (int k = 0; k < 8; k++)
                pre2[k] = __builtin_elementwise_fma(rtv, vf2[ii][k], pre2[k]);
        }
        #pragma unroll
        for (int k = 0; k < 8; k++)
            pre2[k] = bl2[k] + pre2[k] + swap2(pre2[k]);
        if (it == 2) break;
        f32x2 s2v = (f32x2)0.f;
        #pragma unroll
        for (int k = 0; k < 8; k++)
            s2v = __builtin_elementwise_fma(pre2[k], pre2[k], s2v);
        const float pn = sqrtf(s2v[0] + s2v[1]);
        #pragma unroll
        for (int ii = 0; ii < 4; ii++) {
            f32x2 dv = (f32x2)0.f;
            #pragma unroll
            for (int k = 0; k < 8; k++)
                dv = __builtin_elementwise_fma(pre2[k], vf2[ii][k], dv);
            lgr[ii] += __fdividef(dv[0] + dv[1], fmaxf(pn * vn[ii], 1e-8f));
            LG[vv * 72 + (ib + ii) * 8 + oo] = lgr[ii];
        }
        __syncthreads();
        {
            const f32x4 E = *(const f32x4*)&LG[vv * 72 + oo * 8 + half * 4];
            f32x4 exv; float ps = 0.f;
            #pragma unroll
            for (int k = 0; k < 4; k++) { exv[k] = __expf(E[k]); ps += exv[k]; }
            const float sum = ps + swap1(ps);
            const float rs = __fdividef(1.f, sum);
            f32x4 w4;
            #pragma unroll
            for (int k = 0; k < 4; k++) w4[k] = exv[k] * rs;
            *(f32x4*)&RT[vv * 72 + oo * 8 + half * 4] = w4;
        }
        __syncthreads();
        #pragma unroll
        for (int ii = 0; ii < 4; ii++)
            rt[ii] = RT[vv * 72 + (ib + ii) * 8 + oo];
    }
    f32x2 s2v = (f32x2)0.f;
    #pragma unroll
    for (int k = 0; k < 8; k++)
        s2v = __builtin_elementwise_fma(pre2[k], pre2[k], s2v);
    const float n2 = s2v[0] + s2v[1];
    const float nn = sqrtf(n2);
    const float scale = __fdividef(n2, (1.f + n2) * (nn + 1e-12f));
    const size_t sp = (size_t)d * 1024 + h * 32 + vv;
    #pragma unroll
    for (int a = 0; a < 8; a++) {
        const float vlo = pre2[(a >> 1)][a & 1];
        const float vhi = pre2[4 + (a >> 1)][a & 1];
        const float pv  = half ? vhi : vlo;
        out[((size_t)((b * 8 + oo) * 16 + half * 8 + a)) * 32768 + sp] = pv * scale;
    }
}

extern "C" void kernel_launch(void* const* d_in, const int* in_sizes, int n_in,
                              void* d_out, int out_size, void* d_ws, size_t ws_size,
                              hipStream_t stream) {
    const float* x    = (const float*)d_in[0];
    const float* cw   = (const float*)d_in[1];
    const float* cb   = (const float*)d_in[2];
    const float* bias = (const float*)d_in[3];
    float* out = (float*)d_out;
    _Float16* wh2 = (_Float16*)d_ws;                     // 114,688 B
    _Float16* xt  = (_Float16*)((char*)d_ws + 114688);   // 20,123,648 B

    hipLaunchKernelGGL(prep_all, dim3(744), dim3(256), 0, stream, x, cw, xt, wh2);
    hipLaunchKernelGGL(caps_mfma_kernel, dim3(2048), dim3(512), 0, stream,
                       xt, wh2, cb, bias, out);
}